// Round 2
// baseline (1573.831 us; speedup 1.0000x reference)
//
#include <hip/hip_runtime.h>
#include <cstdint>
#include <cstddef>

typedef unsigned short u16;
typedef __bf16 bf16x8 __attribute__((ext_vector_type(8)));
typedef float f32x4 __attribute__((ext_vector_type(4)));
typedef unsigned short u16x8 __attribute__((ext_vector_type(8)));
typedef unsigned short u16x4 __attribute__((ext_vector_type(4)));

__device__ __forceinline__ u16 f2bf(float f) {
  union { float f; unsigned u; } x; x.f = f;
  unsigned r = x.u + 0x7fffu + ((x.u >> 16) & 1u);   // RNE
  return (u16)(r >> 16);
}
__device__ __forceinline__ float bf2f(u16 u) {
  union { unsigned u; float f; } x; x.u = ((unsigned)u) << 16;
  return x.f;
}

// ---------------------------------------------------------------------------
// GEMM: C[M][N] = A[M][K] @ B + bias, B given transposed as Bt[N][K] bf16.
// A fp32 (converted during LDS staging) or bf16.
// 128x128 tile, BK=32, 4 waves (2x2 of 64x64), mfma_f32_16x16x32_bf16.
// ---------------------------------------------------------------------------
template<int A_F32, int OUT_BF16, int RELU>
__global__ __launch_bounds__(256) void gemm_bt(
    const void* __restrict__ Ap, const u16* __restrict__ Bt,
    const float* __restrict__ bias, void* __restrict__ Cp,
    int M, int N, int K)
{
  __shared__ u16 As[128][32];
  __shared__ u16 Bs[128][32];
  const int tid  = threadIdx.x;
  const int row0 = blockIdx.x * 128, col0 = blockIdx.y * 128;
  const int lane = tid & 63, w = tid >> 6;
  const int wr = (w >> 1) * 64, wc = (w & 1) * 64;
  const int fr = lane & 15, fg = lane >> 4;   // fragment row / k-group

  f32x4 acc[4][4] = {};

  for (int k0 = 0; k0 < K; k0 += 32) {
    if (A_F32) {
      const float* A = (const float*)Ap;
      const int ar = tid >> 3, ak = (tid & 7) << 2;   // 8 thr/row, 4 floats each
      #pragma unroll
      for (int p = 0; p < 4; ++p) {
        f32x4 v = *(const f32x4*)&A[(size_t)(row0 + ar + 32*p) * K + k0 + ak];
        u16x4 o = { f2bf(v[0]), f2bf(v[1]), f2bf(v[2]), f2bf(v[3]) };
        *(u16x4*)&As[ar + 32*p][ak] = o;
      }
    } else {
      const u16* A = (const u16*)Ap;
      const int ar = tid >> 2, ak = (tid & 3) << 3;   // 4 thr/row, 8 bf16 each
      #pragma unroll
      for (int p = 0; p < 2; ++p)
        *(u16x8*)&As[ar + 64*p][ak] =
            *(const u16x8*)&A[(size_t)(row0 + ar + 64*p) * K + k0 + ak];
    }
    {
      const int br = tid >> 2, bk2 = (tid & 3) << 3;
      #pragma unroll
      for (int p = 0; p < 2; ++p)
        *(u16x8*)&Bs[br + 64*p][bk2] =
            *(const u16x8*)&Bt[(size_t)(col0 + br + 64*p) * K + k0 + bk2];
    }
    __syncthreads();
    bf16x8 af[4], bfr[4];
    #pragma unroll
    for (int i = 0; i < 4; ++i) af[i]  = *(const bf16x8*)&As[wr + i*16 + fr][fg*8];
    #pragma unroll
    for (int j = 0; j < 4; ++j) bfr[j] = *(const bf16x8*)&Bs[wc + j*16 + fr][fg*8];
    #pragma unroll
    for (int i = 0; i < 4; ++i)
      #pragma unroll
      for (int j = 0; j < 4; ++j)
        acc[i][j] = __builtin_amdgcn_mfma_f32_16x16x32_bf16(af[i], bfr[j], acc[i][j], 0, 0, 0);
    __syncthreads();
  }

  // epilogue: D[row=fg*4+t][col=fr] per 16x16 fragment (m89-verified mapping)
  #pragma unroll
  for (int j = 0; j < 4; ++j) {
    const int c  = col0 + wc + j*16 + fr;
    const float bv = bias[c];
    #pragma unroll
    for (int i = 0; i < 4; ++i) {
      #pragma unroll
      for (int t = 0; t < 4; ++t) {
        const int r = row0 + wr + i*16 + fg*4 + t;
        float v = acc[i][j][t] + bv;
        if (RELU) v = v > 0.f ? v : 0.f;
        if (OUT_BF16) ((u16*)Cp)[(size_t)r * N + c] = f2bf(v);
        else          ((float*)Cp)[(size_t)r * N + c] = v;
      }
    }
  }
}

// ---------------------------------------------------------------------------
// Windowed attention: one block per window. 8 heads x 32 q-rows = 256 threads;
// each thread owns one (head, q) row: 32-wide softmax fully in registers.
// O may alias Q (window-local; all reads staged to LDS before any store).
// ---------------------------------------------------------------------------
__global__ __launch_bounds__(256) void attn_win(
    const u16* Q, const u16* __restrict__ K,
    const u16* __restrict__ V, u16* O)
{
  __shared__ u16 Qs[32][256];
  __shared__ u16 Ks[32][256];
  __shared__ u16 Vs[32][256];
  const int tid = threadIdx.x;
  const size_t base = (size_t)blockIdx.x * (32 * 256);
  #pragma unroll
  for (int p = 0; p < 4; ++p) {
    const int c = tid + p * 256;
    const int r = c >> 5, cc = (c & 31) << 3;
    *(u16x8*)&Qs[r][cc] = *(const u16x8*)&Q[base + (size_t)r * 256 + cc];
    *(u16x8*)&Ks[r][cc] = *(const u16x8*)&K[base + (size_t)r * 256 + cc];
    *(u16x8*)&Vs[r][cc] = *(const u16x8*)&V[base + (size_t)r * 256 + cc];
  }
  __syncthreads();
  const int h = tid >> 5, q = tid & 31;
  const int co = h << 5;

  float qr[32];
  #pragma unroll
  for (int d8 = 0; d8 < 4; ++d8) {
    u16x8 v = *(const u16x8*)&Qs[q][co + d8*8];
    #pragma unroll
    for (int j2 = 0; j2 < 8; ++j2) qr[d8*8 + j2] = bf2f(v[j2]);
  }

  float s[32];
  float mx = -1e30f;
  const float scale = 0.17677669529663687f;   // 1/sqrt(32)
  #pragma unroll
  for (int k = 0; k < 32; ++k) {
    float a = 0.f;
    #pragma unroll
    for (int d8 = 0; d8 < 4; ++d8) {
      u16x8 v = *(const u16x8*)&Ks[k][co + d8*8];
      #pragma unroll
      for (int j2 = 0; j2 < 8; ++j2) a += qr[d8*8 + j2] * bf2f(v[j2]);
    }
    a *= scale;
    s[k] = a;
    mx = fmaxf(mx, a);
  }
  float sum = 0.f;
  #pragma unroll
  for (int k = 0; k < 32; ++k) { float e = __expf(s[k] - mx); s[k] = e; sum += e; }
  const float inv = 1.f / sum;

  float o[32];
  #pragma unroll
  for (int d = 0; d < 32; ++d) o[d] = 0.f;
  #pragma unroll
  for (int k = 0; k < 32; ++k) {
    const float p = s[k];
    #pragma unroll
    for (int d8 = 0; d8 < 4; ++d8) {
      u16x8 v = *(const u16x8*)&Vs[k][co + d8*8];
      #pragma unroll
      for (int j2 = 0; j2 < 8; ++j2) o[d8*8 + j2] += p * bf2f(v[j2]);
    }
  }
  #pragma unroll
  for (int d8 = 0; d8 < 4; ++d8) {
    u16x8 ov;
    #pragma unroll
    for (int j2 = 0; j2 < 8; ++j2) ov[j2] = f2bf(o[d8*8 + j2] * inv);
    *(u16x8*)&O[base + (size_t)q * 256 + co + d8*8] = ov;
  }
}

// ---------------------------------------------------------------------------
// Fused residual + LayerNorm over D=256. One wave per token row.
// X fp32, R bf16; Y fp32 or bf16. Y may alias X (per-lane read-then-write).
// ---------------------------------------------------------------------------
template<int OUT_BF16>
__global__ __launch_bounds__(256) void ln_resid(
    const float* X, const u16* __restrict__ R,
    const float* __restrict__ g, const float* __restrict__ be,
    void* Y)
{
  const int tid = threadIdx.x;
  const int lane = tid & 63, w = tid >> 6;
  const size_t row = (size_t)blockIdx.x * 4 + w;
  const size_t off = row * 256 + (size_t)(lane << 2);
  f32x4 x = *(const f32x4*)&X[off];
  u16x4 rb = *(const u16x4*)&R[off];
  const float v0 = x[0] + bf2f(rb[0]), v1 = x[1] + bf2f(rb[1]);
  const float v2 = x[2] + bf2f(rb[2]), v3 = x[3] + bf2f(rb[3]);
  float s  = v0 + v1 + v2 + v3;
  float s2 = v0*v0 + v1*v1 + v2*v2 + v3*v3;
  #pragma unroll
  for (int d = 1; d < 64; d <<= 1) {
    s  += __shfl_xor(s,  d, 64);
    s2 += __shfl_xor(s2, d, 64);
  }
  const float m   = s  * (1.f/256.f);
  const float var = s2 * (1.f/256.f) - m*m;
  const float rs  = rsqrtf(var + 1e-5f);
  f32x4 gg = *(const f32x4*)&g[lane << 2];
  f32x4 bb = *(const f32x4*)&be[lane << 2];
  const float y0 = (v0 - m) * rs * gg[0] + bb[0];
  const float y1 = (v1 - m) * rs * gg[1] + bb[1];
  const float y2 = (v2 - m) * rs * gg[2] + bb[2];
  const float y3 = (v3 - m) * rs * gg[3] + bb[3];
  if (OUT_BF16) {
    u16x4 o = { f2bf(y0), f2bf(y1), f2bf(y2), f2bf(y3) };
    *(u16x4*)((u16*)Y + off) = o;
  } else {
    f32x4 o; o[0] = y0; o[1] = y1; o[2] = y2; o[3] = y3;
    *(f32x4*)((float*)Y + off) = o;
  }
}

// ---------------------------------------------------------------------------
// Weight prep: W[K][N] fp32 -> Wt[N][K] bf16 (transpose + convert)
// ---------------------------------------------------------------------------
__global__ __launch_bounds__(256) void wprep(
    const float* __restrict__ W, u16* __restrict__ Wt, int K, int N)
{
  const int idx = blockIdx.x * 256 + threadIdx.x;
  if (idx >= K * N) return;
  const int k = idx / N, n = idx - k * N;
  Wt[(size_t)n * K + k] = f2bf(W[idx]);
}

// fp32 -> bf16 bulk convert, 8 elements/thread, exact-cover grid
__global__ __launch_bounds__(256) void f32_to_bf16(
    const float* __restrict__ X, u16* __restrict__ Y)
{
  const size_t i = ((size_t)blockIdx.x * 256 + threadIdx.x) * 8;
  f32x4 a = *(const f32x4*)&X[i];
  f32x4 b = *(const f32x4*)&X[i + 4];
  u16x8 o = { f2bf(a[0]), f2bf(a[1]), f2bf(a[2]), f2bf(a[3]),
              f2bf(b[0]), f2bf(b[1]), f2bf(b[2]), f2bf(b[3]) };
  *(u16x8*)&Y[i] = o;
}

// ---------------------------------------------------------------------------
extern "C" void kernel_launch(void* const* d_in, const int* in_sizes, int n_in,
                              void* d_out, int out_size, void* d_ws, size_t ws_size,
                              hipStream_t stream)
{
  const float* query  = (const float*)d_in[0];
  const float* keyval = (const float*)d_in[1];
  const float* Wq = (const float*)d_in[2];  const float* bq  = (const float*)d_in[3];
  const float* Wk = (const float*)d_in[4];  const float* bk  = (const float*)d_in[5];
  const float* Wv = (const float*)d_in[6];  const float* bv  = (const float*)d_in[7];
  const float* Wo = (const float*)d_in[8];  const float* bo  = (const float*)d_in[9];
  const float* g1 = (const float*)d_in[10]; const float* be1 = (const float*)d_in[11];
  const float* W1 = (const float*)d_in[12]; const float* bf1 = (const float*)d_in[13];
  const float* W2 = (const float*)d_in[14]; const float* bf2 = (const float*)d_in[15];
  const float* g2 = (const float*)d_in[16]; const float* be2 = (const float*)d_in[17];

  const int M  = 131072;     // B*L token rows
  const int MC = 32768;      // row chunk (window-aligned), 4 chunks
  char* ws = (char*)d_ws;
  // Workspace layout (~194 MiB total; d_out doubles as the fp32 scratch):
  //   [0,64MiB)    : xcur bf16 [M][256]  (layer input / LN1 residual)
  //   [64,128MiB)  : x1   bf16 [M][256]  (post-LN1 / LN2 residual)
  //   [128,192MiB) : work region, reused per chunk:
  //                    QKV phase: Qc(16MiB) Kc(16MiB) Vc(16MiB); O in-place over Qc
  //                    FFN phase: Hc bf16 [MC][1024] = 64MiB
  //   [192MiB,..)  : bf16 transposed weights (~1.6MiB)
  //   d_out        : tmp fp32 [M][256] (pre-LN GEMM outputs; final LN in-place)
  u16*  xcur = (u16*)ws;
  u16*  x1   = (u16*)(ws + (64ull  << 20));
  char* work =        ws + (128ull << 20);
  u16*  Qc   = (u16*)work;
  u16*  Kc   = (u16*)(work + (16ull << 20));
  u16*  Vc   = (u16*)(work + (32ull << 20));
  u16*  Hc   = (u16*)work;                      // [MC][1024] bf16
  u16*  WqT  = (u16*)(ws + (192ull << 20));
  u16*  WkT  = WqT + 65536;
  u16*  WvT  = WkT + 65536;
  u16*  WoT  = WvT + 65536;
  u16*  W1T  = WoT + 65536;    // [1024][256]
  u16*  W2T  = W1T + 262144;   // [256][1024]
  float* tmp = (float*)d_out;  // [M][256] fp32

  wprep<<<256,  256, 0, stream>>>(Wq, WqT, 256, 256);
  wprep<<<256,  256, 0, stream>>>(Wk, WkT, 256, 256);
  wprep<<<256,  256, 0, stream>>>(Wv, WvT, 256, 256);
  wprep<<<256,  256, 0, stream>>>(Wo, WoT, 256, 256);
  wprep<<<1024, 256, 0, stream>>>(W1, W1T, 256, 1024);
  wprep<<<1024, 256, 0, stream>>>(W2, W2T, 1024, 256);
  f32_to_bf16<<<16384, 256, 0, stream>>>(query, xcur);   // M*256/8/256

  // NOTE: jnp.roll(x, -16, axis=1) permutes whole windows; the encoder layer is
  // window-local and position-independent, so roll + layer + unroll == layer.
  // Both rolls are elided (bit-exact equivalence).
  auto run_layer = [&](const float* kv_f32, int last) {
    // --- attention block, chunked over rows (all ops window-local) ---
    for (int c = 0; c < 4; ++c) {
      const size_t ro = (size_t)c * MC;
      gemm_bt<0,1,0><<<dim3(MC/128, 2), 256, 0, stream>>>(
          xcur + ro * 256, WqT, bq, Qc, MC, 256, 256);
      if (kv_f32) {
        gemm_bt<1,1,0><<<dim3(MC/128, 2), 256, 0, stream>>>(
            kv_f32 + ro * 256, WkT, bk, Kc, MC, 256, 256);
        gemm_bt<1,1,0><<<dim3(MC/128, 2), 256, 0, stream>>>(
            kv_f32 + ro * 256, WvT, bv, Vc, MC, 256, 256);
      } else {
        gemm_bt<0,1,0><<<dim3(MC/128, 2), 256, 0, stream>>>(
            xcur + ro * 256, WkT, bk, Kc, MC, 256, 256);
        gemm_bt<0,1,0><<<dim3(MC/128, 2), 256, 0, stream>>>(
            xcur + ro * 256, WvT, bv, Vc, MC, 256, 256);
      }
      attn_win<<<MC/32, 256, 0, stream>>>(Qc, Kc, Vc, Qc);   // O in-place
      gemm_bt<0,0,0><<<dim3(MC/128, 2), 256, 0, stream>>>(
          Qc, WoT, bo, tmp + ro * 256, MC, 256, 256);
    }
    ln_resid<1><<<M/4, 256, 0, stream>>>(tmp, xcur, g1, be1, x1);
    // --- FFN, chunked (Hc reuses the QKV work region) ---
    for (int c = 0; c < 4; ++c) {
      const size_t ro = (size_t)c * MC;
      gemm_bt<0,1,1><<<dim3(MC/128, 8), 256, 0, stream>>>(
          x1 + ro * 256, W1T, bf1, Hc, MC, 1024, 256);
      gemm_bt<0,0,0><<<dim3(MC/128, 2), 256, 0, stream>>>(
          Hc, W2T, bf2, tmp + ro * 256, MC, 256, 1024);
    }
    if (last) ln_resid<0><<<M/4, 256, 0, stream>>>(tmp, x1, g2, be2, d_out); // in-place
    else      ln_resid<1><<<M/4, 256, 0, stream>>>(tmp, x1, g2, be2, xcur);
  };

  run_layer(keyval, 0);    // layer 1: q=bf16(query) in xcur, kv=keyval fp32
  run_layer(nullptr, 1);   // layer 2: q=kv=xcur, final LN -> d_out fp32
}

// Round 3
// 1527.933 us; speedup vs baseline: 1.0300x; 1.0300x over previous
//
#include <hip/hip_runtime.h>
#include <cstdint>
#include <cstddef>

typedef unsigned short u16;
typedef __bf16 bf16x8 __attribute__((ext_vector_type(8)));
typedef float f32x4 __attribute__((ext_vector_type(4)));
typedef unsigned short u16x8 __attribute__((ext_vector_type(8)));
typedef unsigned short u16x4 __attribute__((ext_vector_type(4)));

__device__ __forceinline__ u16 f2bf(float f) {
  union { float f; unsigned u; } x; x.f = f;
  unsigned r = x.u + 0x7fffu + ((x.u >> 16) & 1u);   // RNE
  return (u16)(r >> 16);
}
__device__ __forceinline__ float bf2f(u16 u) {
  union { unsigned u; float f; } x; x.u = ((unsigned)u) << 16;
  return x.f;
}
// async global->LDS, 16B per lane; LDS dest is wave-uniform base + lane*16
__device__ __forceinline__ void gload16(const void* g, void* l) {
  __builtin_amdgcn_global_load_lds(
      (const __attribute__((address_space(1))) unsigned int*)g,
      (__attribute__((address_space(3))) unsigned int*)l, 16, 0, 0);
}

// ---------------------------------------------------------------------------
// GEMM: C[(nwg/gy*128)][N] = A[.][K](lda) @ Bt^T + bias. Bt[N][K] bf16.
// 128x128 tile, BK=32, 4 waves (2x2 of 64x64), mfma_f32_16x16x32_bf16.
// 1-D grid; col-fastest decomposition + bijective XCD chunking (nwg%8==0)
// so column-blocks sharing an A row-panel land on one XCD's L2.
// A bf16 (global_load_lds staging) or fp32 (VALU convert staging).
// ---------------------------------------------------------------------------
template<int A_F32, int OUT_BF16, int RELU>
__global__ __launch_bounds__(256) void gemm_bt(
    const void* __restrict__ Ap, int lda, const u16* __restrict__ Bt,
    const float* __restrict__ bias, void* __restrict__ Cp,
    int N, int K, int gy)
{
  __shared__ u16 As[128][32];
  __shared__ u16 Bs[128][32];
  const int tid  = threadIdx.x;
  const int lane = tid & 63, w = tid >> 6;
  const int nwg = gridDim.x, o = blockIdx.x;
  const int lid = (o & 7) * (nwg >> 3) + (o >> 3);   // contiguous lid -> same XCD
  const int by = lid % gy, bx = lid / gy;
  const int row0 = bx * 128, col0 = by * 128;
  const int wr = (w >> 1) * 64, wc = (w & 1) * 64;
  const int fr = lane & 15, fg = lane >> 4;          // fragment row / k-group
  // gload lane mapping: wave w stages LDS rows [w*32, w*32+32)
  const int grow  = (w << 5) + (lane >> 2);          // +16 on second issue
  const int gcolB = (lane & 3) << 4;                 // byte offset within row

  f32x4 acc[4][4] = {};

  for (int k0 = 0; k0 < K; k0 += 32) {
    if (A_F32) {
      const float* A = (const float*)Ap;
      const int ar = tid >> 3, ak = (tid & 7) << 2;   // 8 thr/row, 4 floats
      #pragma unroll
      for (int p = 0; p < 4; ++p) {
        f32x4 v = *(const f32x4*)&A[(size_t)(row0 + ar + 32*p) * lda + k0 + ak];
        u16x4 q = { f2bf(v[0]), f2bf(v[1]), f2bf(v[2]), f2bf(v[3]) };
        *(u16x4*)&As[ar + 32*p][ak] = q;
      }
    } else {
      const char* A = (const char*)Ap;
      #pragma unroll
      for (int h = 0; h < 2; ++h)
        gload16(A + ((size_t)(row0 + grow + h*16) * lda + k0) * 2 + gcolB,
                &As[(w << 5) + h*16][0]);
    }
    {
      const char* B = (const char*)Bt;
      #pragma unroll
      for (int h = 0; h < 2; ++h)
        gload16(B + ((size_t)(col0 + grow + h*16) * K + k0) * 2 + gcolB,
                &Bs[(w << 5) + h*16][0]);
    }
    __syncthreads();
    bf16x8 af[4], bfr[4];
    #pragma unroll
    for (int i = 0; i < 4; ++i) af[i]  = *(const bf16x8*)&As[wr + i*16 + fr][fg*8];
    #pragma unroll
    for (int j = 0; j < 4; ++j) bfr[j] = *(const bf16x8*)&Bs[wc + j*16 + fr][fg*8];
    #pragma unroll
    for (int i = 0; i < 4; ++i)
      #pragma unroll
      for (int j = 0; j < 4; ++j)
        acc[i][j] = __builtin_amdgcn_mfma_f32_16x16x32_bf16(af[i], bfr[j], acc[i][j], 0, 0, 0);
    __syncthreads();
  }

  // epilogue: D[row=fg*4+t][col=fr] per 16x16 fragment (m89-verified mapping)
  #pragma unroll
  for (int j = 0; j < 4; ++j) {
    const int c  = col0 + wc + j*16 + fr;
    const float bv = bias[c];
    #pragma unroll
    for (int i = 0; i < 4; ++i) {
      #pragma unroll
      for (int t = 0; t < 4; ++t) {
        const int r = row0 + wr + i*16 + fg*4 + t;
        float v = acc[i][j][t] + bv;
        if (RELU) v = v > 0.f ? v : 0.f;
        if (OUT_BF16) ((u16*)Cp)[(size_t)r * N + c] = f2bf(v);
        else          ((float*)Cp)[(size_t)r * N + c] = v;
      }
    }
  }
}

// ---------------------------------------------------------------------------
// Windowed attention, strided I/O: one block per window; 8 heads x 32 q-rows.
// Each thread owns one (head, q) row: 32-wide softmax fully in registers.
// O may alias Q/K/V buffers (window-local; all reads staged to LDS first).
// ---------------------------------------------------------------------------
__global__ __launch_bounds__(256) void attn_win(
    const u16* Q, int sq, const u16* K, int sk,
    const u16* V, int sv, u16* O, int so)
{
  __shared__ u16 Qs[32][256];
  __shared__ u16 Ks[32][256];
  __shared__ u16 Vs[32][256];
  const int tid = threadIdx.x;
  const size_t w0 = (size_t)blockIdx.x * 32;
  #pragma unroll
  for (int p = 0; p < 4; ++p) {
    const int c = tid + p * 256;
    const int r = c >> 5, cc = (c & 31) << 3;
    *(u16x8*)&Qs[r][cc] = *(const u16x8*)&Q[(w0 + r) * sq + cc];
    *(u16x8*)&Ks[r][cc] = *(const u16x8*)&K[(w0 + r) * sk + cc];
    *(u16x8*)&Vs[r][cc] = *(const u16x8*)&V[(w0 + r) * sv + cc];
  }
  __syncthreads();
  const int h = tid >> 5, q = tid & 31;
  const int co = h << 5;

  float qr[32];
  #pragma unroll
  for (int d8 = 0; d8 < 4; ++d8) {
    u16x8 v = *(const u16x8*)&Qs[q][co + d8*8];
    #pragma unroll
    for (int j2 = 0; j2 < 8; ++j2) qr[d8*8 + j2] = bf2f(v[j2]);
  }

  float s[32];
  float mx = -1e30f;
  const float scale = 0.17677669529663687f;   // 1/sqrt(32)
  #pragma unroll
  for (int k = 0; k < 32; ++k) {
    float a = 0.f;
    #pragma unroll
    for (int d8 = 0; d8 < 4; ++d8) {
      u16x8 v = *(const u16x8*)&Ks[k][co + d8*8];
      #pragma unroll
      for (int j2 = 0; j2 < 8; ++j2) a += qr[d8*8 + j2] * bf2f(v[j2]);
    }
    a *= scale;
    s[k] = a;
    mx = fmaxf(mx, a);
  }
  float sum = 0.f;
  #pragma unroll
  for (int k = 0; k < 32; ++k) { float e = __expf(s[k] - mx); s[k] = e; sum += e; }
  const float inv = 1.f / sum;

  float oa[32];
  #pragma unroll
  for (int d = 0; d < 32; ++d) oa[d] = 0.f;
  #pragma unroll
  for (int k = 0; k < 32; ++k) {
    const float p = s[k];
    #pragma unroll
    for (int d8 = 0; d8 < 4; ++d8) {
      u16x8 v = *(const u16x8*)&Vs[k][co + d8*8];
      #pragma unroll
      for (int j2 = 0; j2 < 8; ++j2) oa[d8*8 + j2] += p * bf2f(v[j2]);
    }
  }
  #pragma unroll
  for (int d8 = 0; d8 < 4; ++d8) {
    u16x8 ov;
    #pragma unroll
    for (int j2 = 0; j2 < 8; ++j2) ov[j2] = f2bf(oa[d8*8 + j2] * inv);
    *(u16x8*)&O[(w0 + q) * so + co + d8*8] = ov;
  }
}

// ---------------------------------------------------------------------------
// Fused residual + LayerNorm over D=256. One wave per token row.
// X fp32, R bf16; Y fp32 or bf16. Y may alias X (per-lane read-then-write).
// ---------------------------------------------------------------------------
template<int OUT_BF16>
__global__ __launch_bounds__(256) void ln_resid(
    const float* X, const u16* __restrict__ R,
    const float* __restrict__ g, const float* __restrict__ be,
    void* Y)
{
  const int tid = threadIdx.x;
  const int lane = tid & 63, w = tid >> 6;
  const size_t row = (size_t)blockIdx.x * 4 + w;
  const size_t off = row * 256 + (size_t)(lane << 2);
  f32x4 x = *(const f32x4*)&X[off];
  u16x4 rb = *(const u16x4*)&R[off];
  const float v0 = x[0] + bf2f(rb[0]), v1 = x[1] + bf2f(rb[1]);
  const float v2 = x[2] + bf2f(rb[2]), v3 = x[3] + bf2f(rb[3]);
  float s  = v0 + v1 + v2 + v3;
  float s2 = v0*v0 + v1*v1 + v2*v2 + v3*v3;
  #pragma unroll
  for (int d = 1; d < 64; d <<= 1) {
    s  += __shfl_xor(s,  d, 64);
    s2 += __shfl_xor(s2, d, 64);
  }
  const float m   = s  * (1.f/256.f);
  const float var = s2 * (1.f/256.f) - m*m;
  const float rs  = rsqrtf(var + 1e-5f);
  f32x4 gg = *(const f32x4*)&g[lane << 2];
  f32x4 bb = *(const f32x4*)&be[lane << 2];
  const float y0 = (v0 - m) * rs * gg[0] + bb[0];
  const float y1 = (v1 - m) * rs * gg[1] + bb[1];
  const float y2 = (v2 - m) * rs * gg[2] + bb[2];
  const float y3 = (v3 - m) * rs * gg[3] + bb[3];
  if (OUT_BF16) {
    u16x4 oo = { f2bf(y0), f2bf(y1), f2bf(y2), f2bf(y3) };
    *(u16x4*)((u16*)Y + off) = oo;
  } else {
    f32x4 oo; oo[0] = y0; oo[1] = y1; oo[2] = y2; oo[3] = y3;
    *(f32x4*)((float*)Y + off) = oo;
  }
}

// ---------------------------------------------------------------------------
// Weight prep: W[K][N] fp32 -> Wt[N][K] bf16 (transpose + convert)
// ---------------------------------------------------------------------------
__global__ __launch_bounds__(256) void wprep(
    const float* __restrict__ W, u16* __restrict__ Wt, int K, int N)
{
  const int idx = blockIdx.x * 256 + threadIdx.x;
  if (idx >= K * N) return;
  const int k = idx / N, n = idx - k * N;
  Wt[(size_t)n * K + k] = f2bf(W[idx]);
}

// concat bq|bk|bv -> 768 floats
__global__ __launch_bounds__(256) void bcat(
    const float* __restrict__ a, const float* __restrict__ b,
    const float* __restrict__ c, float* __restrict__ o)
{
  const int i = blockIdx.x * 256 + threadIdx.x;
  o[i] = i < 256 ? a[i] : (i < 512 ? b[i - 256] : c[i - 512]);
}

// fp32 -> bf16 bulk convert, 8 elements/thread, exact-cover grid
__global__ __launch_bounds__(256) void f32_to_bf16(
    const float* __restrict__ X, u16* __restrict__ Y)
{
  const size_t i = ((size_t)blockIdx.x * 256 + threadIdx.x) * 8;
  f32x4 a = *(const f32x4*)&X[i];
  f32x4 b = *(const f32x4*)&X[i + 4];
  u16x8 o = { f2bf(a[0]), f2bf(a[1]), f2bf(a[2]), f2bf(a[3]),
              f2bf(b[0]), f2bf(b[1]), f2bf(b[2]), f2bf(b[3]) };
  *(u16x8*)&Y[i] = o;
}

// ---------------------------------------------------------------------------
extern "C" void kernel_launch(void* const* d_in, const int* in_sizes, int n_in,
                              void* d_out, int out_size, void* d_ws, size_t ws_size,
                              hipStream_t stream)
{
  const float* query  = (const float*)d_in[0];
  const float* keyval = (const float*)d_in[1];
  const float* Wq = (const float*)d_in[2];  const float* bq  = (const float*)d_in[3];
  const float* Wk = (const float*)d_in[4];  const float* bk  = (const float*)d_in[5];
  const float* Wv = (const float*)d_in[6];  const float* bv  = (const float*)d_in[7];
  const float* Wo = (const float*)d_in[8];  const float* bo  = (const float*)d_in[9];
  const float* g1 = (const float*)d_in[10]; const float* be1 = (const float*)d_in[11];
  const float* W1 = (const float*)d_in[12]; const float* bf1 = (const float*)d_in[13];
  const float* W2 = (const float*)d_in[14]; const float* bf2 = (const float*)d_in[15];
  const float* g2 = (const float*)d_in[16]; const float* be2 = (const float*)d_in[17];

  const int M  = 131072;     // B*L token rows
  const int MC = 32768;      // row chunk (window-aligned), 4 chunks
  char* ws = (char*)d_ws;
  // Workspace (~194 MiB; d_out doubles as the fp32 pre-LN scratch):
  //   [0,64MiB)    : xcur bf16 [M][256]
  //   [64,128MiB)  : x1   bf16 [M][256]
  //   [128,192MiB) : work region per chunk:
  //                    L1 attn: Qc [MC][256] (16MiB) + KVc [MC][512] (32MiB)
  //                    L2 attn: QKVc [MC][768] (48MiB)
  //                    FFN: Hc [MC][1024] (64MiB)
  //   [192MiB,..)  : bf16 weights (1.5MiB) + fused bias (3KiB)
  u16*  xcur = (u16*)ws;
  u16*  x1   = (u16*)(ws + (64ull  << 20));
  char* work =        ws + (128ull << 20);
  u16*  Qc   = (u16*)work;
  u16*  KVc  = (u16*)(work + (16ull << 20));
  u16*  QKVc = (u16*)work;
  u16*  Hc   = (u16*)work;
  u16*  WqkvT = (u16*)(ws + (192ull << 20));   // [768][256]; rows 256.. = Wk|Wv
  u16*  WoT   = WqkvT + 196608;                // [256][256]
  u16*  W1T   = WoT   + 65536;                 // [1024][256]
  u16*  W2T   = W1T   + 262144;                // [256][1024]
  float* bqkv = (float*)(W2T + 262144);        // [768] = bq|bk|bv
  float* tmp  = (float*)d_out;                 // [M][256] fp32

  wprep<<<256,  256, 0, stream>>>(Wq, WqkvT,          256, 256);
  wprep<<<256,  256, 0, stream>>>(Wk, WqkvT +  65536, 256, 256);
  wprep<<<256,  256, 0, stream>>>(Wv, WqkvT + 131072, 256, 256);
  wprep<<<256,  256, 0, stream>>>(Wo, WoT, 256, 256);
  wprep<<<1024, 256, 0, stream>>>(W1, W1T, 256, 1024);
  wprep<<<1024, 256, 0, stream>>>(W2, W2T, 1024, 256);
  bcat<<<3, 256, 0, stream>>>(bq, bk, bv, bqkv);
  f32_to_bf16<<<16384, 256, 0, stream>>>(query, xcur);

  // NOTE: jnp.roll(x, -16, axis=1) permutes whole windows; the encoder layer is
  // window-local and position-independent, so roll + layer + unroll == layer.
  // Both rolls are elided (bit-exact equivalence).
  auto run_layer = [&](const float* kv_f32, int last) {
    for (int c = 0; c < 4; ++c) {
      const size_t ro = (size_t)c * MC;
      if (kv_f32) {   // layer 1: Q from xcur; fused K|V from fp32 keyval
        gemm_bt<0,1,0><<< 512, 256, 0, stream>>>(
            xcur + ro * 256, 256, WqkvT, bqkv, Qc, 256, 256, 2);
        gemm_bt<1,1,0><<<1024, 256, 0, stream>>>(
            kv_f32 + ro * 256, 256, WqkvT + 65536, bqkv + 256, KVc, 512, 256, 4);
        attn_win<<<1024, 256, 0, stream>>>(Qc, 256, KVc, 512, KVc + 256, 512, Qc, 256);
        gemm_bt<0,0,0><<< 512, 256, 0, stream>>>(
            Qc, 256, WoT, bo, tmp + ro * 256, 256, 256, 2);
      } else {        // layer 2: fused Q|K|V from xcur
        gemm_bt<0,1,0><<<1536, 256, 0, stream>>>(
            xcur + ro * 256, 256, WqkvT, bqkv, QKVc, 768, 256, 6);
        attn_win<<<1024, 256, 0, stream>>>(
            QKVc, 768, QKVc + 256, 768, QKVc + 512, 768, QKVc, 768);
        gemm_bt<0,0,0><<< 512, 256, 0, stream>>>(
            QKVc, 768, WoT, bo, tmp + ro * 256, 256, 256, 2);
      }
    }
    ln_resid<1><<<M/4, 256, 0, stream>>>(tmp, xcur, g1, be1, x1);
    for (int c = 0; c < 4; ++c) {
      const size_t ro = (size_t)c * MC;
      gemm_bt<0,1,1><<<2048, 256, 0, stream>>>(
          x1 + ro * 256, 256, W1T, bf1, Hc, 1024, 256, 8);
      gemm_bt<0,0,0><<< 512, 256, 0, stream>>>(
          Hc, 1024, W2T, bf2, tmp + ro * 256, 256, 1024, 2);
    }
    if (last) ln_resid<0><<<M/4, 256, 0, stream>>>(tmp, x1, g2, be2, d_out); // in-place
    else      ln_resid<1><<<M/4, 256, 0, stream>>>(tmp, x1, g2, be2, xcur);
  };

  run_layer(keyval, 0);    // layer 1: q = bf16(query), kv = keyval fp32
  run_layer(nullptr, 1);   // layer 2: q = kv = xcur; final LN -> d_out
}